// Round 16
// baseline (18.948 us; speedup 1.0000x reference)
//
#include <hip/hip_runtime.h>

// SeparableWeightedConv R15: exact R12 champion (16.2us) with ONE delta:
// plain stores instead of nontemporal (nt bypasses L2 write-combining; the
// 6.6TB/s fill reference goes THROUGH L2). Single-variable A/B on the store
// path. Everything else identical: depth-4 pipeline, DPP shifts, combined
// halo loads, fast sqrt.

#define BB 8
#define CC 128
#define NN 8192
#define KK 9

constexpr int CH      = 8;            // channels per block
constexpr int CGROUPS = CC / CH;      // 16
constexpr int LTILE   = 1024;         // 256 thr x 4 l
constexpr int LTILES  = NN / LTILE;   // 8
constexpr int THREADS = 256;

// lane i <- lane i-1  (== __shfl_up(v,1)); lane 0 reads 0 (bound_ctrl)
__device__ __forceinline__ float dpp_up1(float v) {
    int r = __builtin_amdgcn_update_dpp(0, __builtin_bit_cast(int, v),
                                        0x138 /*WAVE_SHR1*/, 0xF, 0xF, true);
    return __builtin_bit_cast(float, r);
}
// lane i <- lane i+1  (== __shfl_down(v,1)); lane 63 reads 0 (bound_ctrl)
__device__ __forceinline__ float dpp_dn1(float v) {
    int r = __builtin_amdgcn_update_dpp(0, __builtin_bit_cast(int, v),
                                        0x130 /*WAVE_SHL1*/, 0xF, 0xF, true);
    return __builtin_bit_cast(float, r);
}

__global__ __launch_bounds__(THREADS)
void sepwconv_kernel(const float* __restrict__ x,
                     const float* __restrict__ coords,
                     const float* __restrict__ sigma,
                     const float* __restrict__ weight,
                     float* __restrict__ out)
{
    const int bid = blockIdx.x;
    const int cg  = bid % CGROUPS;
    const int lt  = (bid / CGROUPS) % LTILES;
    const int b   = bid / (CGROUPS * LTILES);
    const int t   = threadIdx.x;
    const int lane = t & 63;
    const int l0  = lt * LTILE + t * 4;

    const float inv_sigma = 1.0f / sigma[0];

    // edge predicates: lane0 needs left halo quad, lane63 needs right halo quad
    const bool ledge = (lane == 0)  && (l0 >= 4);
    const bool redge = (lane == 63) && (l0 + 8 <= NN);
    const bool edge  = ledge || redge;
    const int  hoff  = (lane == 0) ? -4 : 4;   // per-lane halo offset

    const float* cx = coords + (size_t)(b * 3 + 0) * NN;
    const float* cy = coords + (size_t)(b * 3 + 1) * NN;
    const float* cz = coords + (size_t)(b * 3 + 2) * NN;

    // --- coord center quads + combined halo loads (one vmem op per dim) ---
    float4 cxm = *(const float4*)(cx + l0);
    float4 cym = *(const float4*)(cy + l0);
    float4 czm = *(const float4*)(cz + l0);
    float4 cxH = {0,0,0,0}, cyH = {0,0,0,0}, czH = {0,0,0,0};
    if (edge) {
        cxH = *(const float4*)(cx + l0 + hoff);
        cyH = *(const float4*)(cy + l0 + hoff);
        czH = *(const float4*)(cz + l0 + hoff);
    }

    const float* xbase = x + ((size_t)b * CC + cg * CH) * NN;

    auto loadM = [&](int i) -> float4 {
        return *(const float4*)(xbase + (size_t)i * NN + l0);
    };
    auto loadH = [&](int i) -> float4 {
        float4 h = {0.f, 0.f, 0.f, 0.f};
        if (edge) h = *(const float4*)(xbase + (size_t)i * NN + l0 + hoff);
        return h;
    };

    // --- issue 4 stages before the dw chain (depth-4 pipeline) ---
    float4 M0 = loadM(0), H0 = loadH(0);
    float4 M1 = loadM(1), H1 = loadH(1);
    float4 M2 = loadM(2), H2 = loadH(2);
    float4 M3 = loadM(3), H3 = loadH(3);

    // --- build 12-wide coord windows via DPP wave shifts ---
    auto haloWindow = [&](const float4& M, const float4& H, float* v) {
        v[4] = M.x; v[5] = M.y; v[6] = M.z; v[7] = M.w;
        v[0] = dpp_up1(M.x);
        v[1] = dpp_up1(M.y);
        v[2] = dpp_up1(M.z);
        v[3] = dpp_up1(M.w);
        v[8]  = dpp_dn1(M.x);
        v[9]  = dpp_dn1(M.y);
        v[10] = dpp_dn1(M.z);
        v[11] = dpp_dn1(M.w);
        if (lane == 0)  { v[0] = H.x; v[1] = H.y; v[2] = H.z; v[3] = H.w; }
        if (lane == 63) { v[8] = H.x; v[9] = H.y; v[10] = H.z; v[11] = H.w; }
    };

    float cxv[12], cyv[12], czv[12];
    haloWindow(cxm, cxH, cxv);
    haloWindow(cym, cyH, cyv);
    haloWindow(czm, czH, czv);

    // --- dw[jl][k]: distance weights, shared across channels ---
    float dw[4][KK];
    #pragma unroll
    for (int jl = 0; jl < 4; ++jl) {
        const float ccx = cxv[jl + 4], ccy = cyv[jl + 4], ccz = czv[jl + 4];
        #pragma unroll
        for (int k = 0; k < KK; ++k) {
            const float dx = cxv[jl + k] - ccx;
            const float dy = cyv[jl + k] - ccy;
            const float dz = czv[jl + k] - ccz;
            const float sq = fmaf(dx, dx, fmaf(dy, dy, dz * dz));
            const float dist = __builtin_amdgcn_sqrtf(sq);   // v_sqrt_f32; sqrt(0)==0
            dw[jl][k] = fmaxf(fmaf(-inv_sigma, dist, 1.0f), 0.0f);
        }
    }

    // --- compute one channel from its stage (M + combined halo H) ---
    auto compute = [&](int i, const float4& M, const float4& H) {
        float lx0 = dpp_up1(M.x);
        float lx1 = dpp_up1(M.y);
        float lx2 = dpp_up1(M.z);
        float lx3 = dpp_up1(M.w);
        float rx0 = dpp_dn1(M.x);
        float rx1 = dpp_dn1(M.y);
        float rx2 = dpp_dn1(M.z);
        float rx3 = dpp_dn1(M.w);
        if (lane == 0)  { lx0 = H.x; lx1 = H.y; lx2 = H.z; lx3 = H.w; }
        if (lane == 63) { rx0 = H.x; rx1 = H.y; rx2 = H.z; rx3 = H.w; }

        const float* wr = weight + (size_t)(cg * CH + i) * KK;  // wave-uniform
        float w[KK];
        #pragma unroll
        for (int k = 0; k < KK; ++k) w[k] = wr[k];

        const float xv[12] = {lx0, lx1, lx2, lx3,
                              M.x, M.y, M.z, M.w,
                              rx0, rx1, rx2, rx3};
        float acc[4] = {0.f, 0.f, 0.f, 0.f};
        #pragma unroll
        for (int jl = 0; jl < 4; ++jl)
            #pragma unroll
            for (int k = 0; k < KK; ++k)
                acc[jl] = fmaf(xv[jl + k] * dw[jl][k], w[k], acc[jl]);

        float4 o; o.x = acc[0]; o.y = acc[1]; o.z = acc[2]; o.w = acc[3];
        *(float4*)(out + ((size_t)b * CC + cg * CH + i) * NN + l0) = o;   // plain store
    };

    // --- depth-4 rolling pipeline: compute i, issue stage i+4 ---
    compute(0, M0, H0); float4 M4 = loadM(4), H4 = loadH(4);
    compute(1, M1, H1); float4 M5 = loadM(5), H5 = loadH(5);
    compute(2, M2, H2); float4 M6 = loadM(6), H6 = loadH(6);
    compute(3, M3, H3); float4 M7 = loadM(7), H7 = loadH(7);
    compute(4, M4, H4);
    compute(5, M5, H5);
    compute(6, M6, H6);
    compute(7, M7, H7);
}

extern "C" void kernel_launch(void* const* d_in, const int* in_sizes, int n_in,
                              void* d_out, int out_size, void* d_ws, size_t ws_size,
                              hipStream_t stream) {
    const float* x      = (const float*)d_in[0];
    const float* coords = (const float*)d_in[1];
    const float* sigma  = (const float*)d_in[2];
    const float* weight = (const float*)d_in[3];
    float* out = (float*)d_out;

    dim3 grid(BB * LTILES * CGROUPS);   // 1024 blocks
    sepwconv_kernel<<<grid, THREADS, 0, stream>>>(x, coords, sigma, weight, out);
}

// Round 17
// 18.231 us; speedup vs baseline: 1.0393x; 1.0393x over previous
//
#include <hip/hip_runtime.h>

// SeparableWeightedConv R16: R12 champion (16.2us) + ONE delta: nontemporal
// LOADS for the x stream (read exactly once; halo reuse is in-register via
// DPP, not cache). Mechanism proven by R15: nt-stores won 2.7us by keeping
// the write stream out of L2 -- apply same to the read stream. Coords stay
// plain (L2-reused across 16 channel-group blocks).

#define BB 8
#define CC 128
#define NN 8192
#define KK 9

constexpr int CH      = 8;            // channels per block
constexpr int CGROUPS = CC / CH;      // 16
constexpr int LTILE   = 1024;         // 256 thr x 4 l
constexpr int LTILES  = NN / LTILE;   // 8
constexpr int THREADS = 256;

typedef float vfloat4 __attribute__((ext_vector_type(4)));

// lane i <- lane i-1  (== __shfl_up(v,1)); lane 0 reads 0 (bound_ctrl)
__device__ __forceinline__ float dpp_up1(float v) {
    int r = __builtin_amdgcn_update_dpp(0, __builtin_bit_cast(int, v),
                                        0x138 /*WAVE_SHR1*/, 0xF, 0xF, true);
    return __builtin_bit_cast(float, r);
}
// lane i <- lane i+1  (== __shfl_down(v,1)); lane 63 reads 0 (bound_ctrl)
__device__ __forceinline__ float dpp_dn1(float v) {
    int r = __builtin_amdgcn_update_dpp(0, __builtin_bit_cast(int, v),
                                        0x130 /*WAVE_SHL1*/, 0xF, 0xF, true);
    return __builtin_bit_cast(float, r);
}

__global__ __launch_bounds__(THREADS)
void sepwconv_kernel(const float* __restrict__ x,
                     const float* __restrict__ coords,
                     const float* __restrict__ sigma,
                     const float* __restrict__ weight,
                     float* __restrict__ out)
{
    const int bid = blockIdx.x;
    const int cg  = bid % CGROUPS;
    const int lt  = (bid / CGROUPS) % LTILES;
    const int b   = bid / (CGROUPS * LTILES);
    const int t   = threadIdx.x;
    const int lane = t & 63;
    const int l0  = lt * LTILE + t * 4;

    const float inv_sigma = 1.0f / sigma[0];

    // edge predicates: lane0 needs left halo quad, lane63 needs right halo quad
    const bool ledge = (lane == 0)  && (l0 >= 4);
    const bool redge = (lane == 63) && (l0 + 8 <= NN);
    const bool edge  = ledge || redge;
    const int  hoff  = (lane == 0) ? -4 : 4;   // per-lane halo offset

    const float* cx = coords + (size_t)(b * 3 + 0) * NN;
    const float* cy = coords + (size_t)(b * 3 + 1) * NN;
    const float* cz = coords + (size_t)(b * 3 + 2) * NN;

    // --- coord center quads + combined halo loads (one vmem op per dim) ---
    float4 cxm = *(const float4*)(cx + l0);
    float4 cym = *(const float4*)(cy + l0);
    float4 czm = *(const float4*)(cz + l0);
    float4 cxH = {0,0,0,0}, cyH = {0,0,0,0}, czH = {0,0,0,0};
    if (edge) {
        cxH = *(const float4*)(cx + l0 + hoff);
        cyH = *(const float4*)(cy + l0 + hoff);
        czH = *(const float4*)(cz + l0 + hoff);
    }

    const float* xbase = x + ((size_t)b * CC + cg * CH) * NN;

    // x loads: NONTEMPORAL (stream, no L2 residency)
    auto loadM = [&](int i) -> float4 {
        vfloat4 v = __builtin_nontemporal_load(
            (const vfloat4*)(xbase + (size_t)i * NN + l0));
        return make_float4(v.x, v.y, v.z, v.w);
    };
    auto loadH = [&](int i) -> float4 {
        float4 h = {0.f, 0.f, 0.f, 0.f};
        if (edge) {
            vfloat4 v = __builtin_nontemporal_load(
                (const vfloat4*)(xbase + (size_t)i * NN + l0 + hoff));
            h = make_float4(v.x, v.y, v.z, v.w);
        }
        return h;
    };

    // --- issue 4 stages before the dw chain (depth-4 pipeline) ---
    float4 M0 = loadM(0), H0 = loadH(0);
    float4 M1 = loadM(1), H1 = loadH(1);
    float4 M2 = loadM(2), H2 = loadH(2);
    float4 M3 = loadM(3), H3 = loadH(3);

    // --- build 12-wide coord windows via DPP wave shifts ---
    auto haloWindow = [&](const float4& M, const float4& H, float* v) {
        v[4] = M.x; v[5] = M.y; v[6] = M.z; v[7] = M.w;
        v[0] = dpp_up1(M.x);
        v[1] = dpp_up1(M.y);
        v[2] = dpp_up1(M.z);
        v[3] = dpp_up1(M.w);
        v[8]  = dpp_dn1(M.x);
        v[9]  = dpp_dn1(M.y);
        v[10] = dpp_dn1(M.z);
        v[11] = dpp_dn1(M.w);
        if (lane == 0)  { v[0] = H.x; v[1] = H.y; v[2] = H.z; v[3] = H.w; }
        if (lane == 63) { v[8] = H.x; v[9] = H.y; v[10] = H.z; v[11] = H.w; }
    };

    float cxv[12], cyv[12], czv[12];
    haloWindow(cxm, cxH, cxv);
    haloWindow(cym, cyH, cyv);
    haloWindow(czm, czH, czv);

    // --- dw[jl][k]: distance weights, shared across channels ---
    float dw[4][KK];
    #pragma unroll
    for (int jl = 0; jl < 4; ++jl) {
        const float ccx = cxv[jl + 4], ccy = cyv[jl + 4], ccz = czv[jl + 4];
        #pragma unroll
        for (int k = 0; k < KK; ++k) {
            const float dx = cxv[jl + k] - ccx;
            const float dy = cyv[jl + k] - ccy;
            const float dz = czv[jl + k] - ccz;
            const float sq = fmaf(dx, dx, fmaf(dy, dy, dz * dz));
            const float dist = __builtin_amdgcn_sqrtf(sq);   // v_sqrt_f32; sqrt(0)==0
            dw[jl][k] = fmaxf(fmaf(-inv_sigma, dist, 1.0f), 0.0f);
        }
    }

    // --- compute one channel from its stage (M + combined halo H) ---
    auto compute = [&](int i, const float4& M, const float4& H) {
        float lx0 = dpp_up1(M.x);
        float lx1 = dpp_up1(M.y);
        float lx2 = dpp_up1(M.z);
        float lx3 = dpp_up1(M.w);
        float rx0 = dpp_dn1(M.x);
        float rx1 = dpp_dn1(M.y);
        float rx2 = dpp_dn1(M.z);
        float rx3 = dpp_dn1(M.w);
        if (lane == 0)  { lx0 = H.x; lx1 = H.y; lx2 = H.z; lx3 = H.w; }
        if (lane == 63) { rx0 = H.x; rx1 = H.y; rx2 = H.z; rx3 = H.w; }

        const float* wr = weight + (size_t)(cg * CH + i) * KK;  // wave-uniform
        float w[KK];
        #pragma unroll
        for (int k = 0; k < KK; ++k) w[k] = wr[k];

        const float xv[12] = {lx0, lx1, lx2, lx3,
                              M.x, M.y, M.z, M.w,
                              rx0, rx1, rx2, rx3};
        float acc[4] = {0.f, 0.f, 0.f, 0.f};
        #pragma unroll
        for (int jl = 0; jl < 4; ++jl)
            #pragma unroll
            for (int k = 0; k < KK; ++k)
                acc[jl] = fmaf(xv[jl + k] * dw[jl][k], w[k], acc[jl]);

        vfloat4 o = {acc[0], acc[1], acc[2], acc[3]};
        __builtin_nontemporal_store(o, (vfloat4*)(out + ((size_t)b * CC + cg * CH + i) * NN + l0));
    };

    // --- depth-4 rolling pipeline: compute i, issue stage i+4 ---
    compute(0, M0, H0); float4 M4 = loadM(4), H4 = loadH(4);
    compute(1, M1, H1); float4 M5 = loadM(5), H5 = loadH(5);
    compute(2, M2, H2); float4 M6 = loadM(6), H6 = loadH(6);
    compute(3, M3, H3); float4 M7 = loadM(7), H7 = loadH(7);
    compute(4, M4, H4);
    compute(5, M5, H5);
    compute(6, M6, H6);
    compute(7, M7, H7);
}

extern "C" void kernel_launch(void* const* d_in, const int* in_sizes, int n_in,
                              void* d_out, int out_size, void* d_ws, size_t ws_size,
                              hipStream_t stream) {
    const float* x      = (const float*)d_in[0];
    const float* coords = (const float*)d_in[1];
    const float* sigma  = (const float*)d_in[2];
    const float* weight = (const float*)d_in[3];
    float* out = (float*)d_out;

    dim3 grid(BB * LTILES * CGROUPS);   // 1024 blocks
    sepwconv_kernel<<<grid, THREADS, 0, stream>>>(x, coords, sigma, weight, out);
}

// Round 18
// 15.753 us; speedup vs baseline: 1.2028x; 1.1573x over previous
//
#include <hip/hip_runtime.h>

// SeparableWeightedConv R17: exact revert to the R12 champion (16.20us).
// Final config: CH=8/1024 blocks, depth-4 rolling load pipeline, DPP wave
// shifts for halo (VALU pipe), combined single-instruction edge halo loads,
// fast v_sqrt_f32, NONTEMPORAL stores (proven +2.7us; nt loads proven -2us,
// stay plain). All single-variable tested over R1-R16.

#define BB 8
#define CC 128
#define NN 8192
#define KK 9

constexpr int CH      = 8;            // channels per block
constexpr int CGROUPS = CC / CH;      // 16
constexpr int LTILE   = 1024;         // 256 thr x 4 l
constexpr int LTILES  = NN / LTILE;   // 8
constexpr int THREADS = 256;

typedef float vfloat4 __attribute__((ext_vector_type(4)));

// lane i <- lane i-1  (== __shfl_up(v,1)); lane 0 reads 0 (bound_ctrl)
__device__ __forceinline__ float dpp_up1(float v) {
    int r = __builtin_amdgcn_update_dpp(0, __builtin_bit_cast(int, v),
                                        0x138 /*WAVE_SHR1*/, 0xF, 0xF, true);
    return __builtin_bit_cast(float, r);
}
// lane i <- lane i+1  (== __shfl_down(v,1)); lane 63 reads 0 (bound_ctrl)
__device__ __forceinline__ float dpp_dn1(float v) {
    int r = __builtin_amdgcn_update_dpp(0, __builtin_bit_cast(int, v),
                                        0x130 /*WAVE_SHL1*/, 0xF, 0xF, true);
    return __builtin_bit_cast(float, r);
}

__global__ __launch_bounds__(THREADS)
void sepwconv_kernel(const float* __restrict__ x,
                     const float* __restrict__ coords,
                     const float* __restrict__ sigma,
                     const float* __restrict__ weight,
                     float* __restrict__ out)
{
    const int bid = blockIdx.x;
    const int cg  = bid % CGROUPS;
    const int lt  = (bid / CGROUPS) % LTILES;
    const int b   = bid / (CGROUPS * LTILES);
    const int t   = threadIdx.x;
    const int lane = t & 63;
    const int l0  = lt * LTILE + t * 4;

    const float inv_sigma = 1.0f / sigma[0];

    // edge predicates: lane0 needs left halo quad, lane63 needs right halo quad
    const bool ledge = (lane == 0)  && (l0 >= 4);
    const bool redge = (lane == 63) && (l0 + 8 <= NN);
    const bool edge  = ledge || redge;
    const int  hoff  = (lane == 0) ? -4 : 4;   // per-lane halo offset

    const float* cx = coords + (size_t)(b * 3 + 0) * NN;
    const float* cy = coords + (size_t)(b * 3 + 1) * NN;
    const float* cz = coords + (size_t)(b * 3 + 2) * NN;

    // --- coord center quads + combined halo loads (one vmem op per dim) ---
    float4 cxm = *(const float4*)(cx + l0);
    float4 cym = *(const float4*)(cy + l0);
    float4 czm = *(const float4*)(cz + l0);
    float4 cxH = {0,0,0,0}, cyH = {0,0,0,0}, czH = {0,0,0,0};
    if (edge) {
        cxH = *(const float4*)(cx + l0 + hoff);
        cyH = *(const float4*)(cy + l0 + hoff);
        czH = *(const float4*)(cz + l0 + hoff);
    }

    const float* xbase = x + ((size_t)b * CC + cg * CH) * NN;

    auto loadM = [&](int i) -> float4 {
        return *(const float4*)(xbase + (size_t)i * NN + l0);
    };
    auto loadH = [&](int i) -> float4 {
        float4 h = {0.f, 0.f, 0.f, 0.f};
        if (edge) h = *(const float4*)(xbase + (size_t)i * NN + l0 + hoff);
        return h;
    };

    // --- issue 4 stages before the dw chain (depth-4 pipeline) ---
    float4 M0 = loadM(0), H0 = loadH(0);
    float4 M1 = loadM(1), H1 = loadH(1);
    float4 M2 = loadM(2), H2 = loadH(2);
    float4 M3 = loadM(3), H3 = loadH(3);

    // --- build 12-wide coord windows via DPP wave shifts ---
    auto haloWindow = [&](const float4& M, const float4& H, float* v) {
        v[4] = M.x; v[5] = M.y; v[6] = M.z; v[7] = M.w;
        v[0] = dpp_up1(M.x);
        v[1] = dpp_up1(M.y);
        v[2] = dpp_up1(M.z);
        v[3] = dpp_up1(M.w);
        v[8]  = dpp_dn1(M.x);
        v[9]  = dpp_dn1(M.y);
        v[10] = dpp_dn1(M.z);
        v[11] = dpp_dn1(M.w);
        if (lane == 0)  { v[0] = H.x; v[1] = H.y; v[2] = H.z; v[3] = H.w; }
        if (lane == 63) { v[8] = H.x; v[9] = H.y; v[10] = H.z; v[11] = H.w; }
    };

    float cxv[12], cyv[12], czv[12];
    haloWindow(cxm, cxH, cxv);
    haloWindow(cym, cyH, cyv);
    haloWindow(czm, czH, czv);

    // --- dw[jl][k]: distance weights, shared across channels ---
    float dw[4][KK];
    #pragma unroll
    for (int jl = 0; jl < 4; ++jl) {
        const float ccx = cxv[jl + 4], ccy = cyv[jl + 4], ccz = czv[jl + 4];
        #pragma unroll
        for (int k = 0; k < KK; ++k) {
            const float dx = cxv[jl + k] - ccx;
            const float dy = cyv[jl + k] - ccy;
            const float dz = czv[jl + k] - ccz;
            const float sq = fmaf(dx, dx, fmaf(dy, dy, dz * dz));
            const float dist = __builtin_amdgcn_sqrtf(sq);   // v_sqrt_f32; sqrt(0)==0
            dw[jl][k] = fmaxf(fmaf(-inv_sigma, dist, 1.0f), 0.0f);
        }
    }

    // --- compute one channel from its stage (M + combined halo H) ---
    auto compute = [&](int i, const float4& M, const float4& H) {
        float lx0 = dpp_up1(M.x);
        float lx1 = dpp_up1(M.y);
        float lx2 = dpp_up1(M.z);
        float lx3 = dpp_up1(M.w);
        float rx0 = dpp_dn1(M.x);
        float rx1 = dpp_dn1(M.y);
        float rx2 = dpp_dn1(M.z);
        float rx3 = dpp_dn1(M.w);
        if (lane == 0)  { lx0 = H.x; lx1 = H.y; lx2 = H.z; lx3 = H.w; }
        if (lane == 63) { rx0 = H.x; rx1 = H.y; rx2 = H.z; rx3 = H.w; }

        const float* wr = weight + (size_t)(cg * CH + i) * KK;  // wave-uniform
        float w[KK];
        #pragma unroll
        for (int k = 0; k < KK; ++k) w[k] = wr[k];

        const float xv[12] = {lx0, lx1, lx2, lx3,
                              M.x, M.y, M.z, M.w,
                              rx0, rx1, rx2, rx3};
        float acc[4] = {0.f, 0.f, 0.f, 0.f};
        #pragma unroll
        for (int jl = 0; jl < 4; ++jl)
            #pragma unroll
            for (int k = 0; k < KK; ++k)
                acc[jl] = fmaf(xv[jl + k] * dw[jl][k], w[k], acc[jl]);

        vfloat4 o = {acc[0], acc[1], acc[2], acc[3]};
        __builtin_nontemporal_store(o, (vfloat4*)(out + ((size_t)b * CC + cg * CH + i) * NN + l0));
    };

    // --- depth-4 rolling pipeline: compute i, issue stage i+4 ---
    compute(0, M0, H0); float4 M4 = loadM(4), H4 = loadH(4);
    compute(1, M1, H1); float4 M5 = loadM(5), H5 = loadH(5);
    compute(2, M2, H2); float4 M6 = loadM(6), H6 = loadH(6);
    compute(3, M3, H3); float4 M7 = loadM(7), H7 = loadH(7);
    compute(4, M4, H4);
    compute(5, M5, H5);
    compute(6, M6, H6);
    compute(7, M7, H7);
}

extern "C" void kernel_launch(void* const* d_in, const int* in_sizes, int n_in,
                              void* d_out, int out_size, void* d_ws, size_t ws_size,
                              hipStream_t stream) {
    const float* x      = (const float*)d_in[0];
    const float* coords = (const float*)d_in[1];
    const float* sigma  = (const float*)d_in[2];
    const float* weight = (const float*)d_in[3];
    float* out = (float*)d_out;

    dim3 grid(BB * LTILES * CGROUPS);   // 1024 blocks
    sepwconv_kernel<<<grid, THREADS, 0, stream>>>(x, coords, sigma, weight, out);
}